// Round 1
// baseline (1796.009 us; speedup 1.0000x reference)
//
#include <hip/hip_runtime.h>
#include <cstdint>
#include <cstddef>

// TransformerXL forward (B=4,N=1024,D=1024,H=16,DH=64,DEPTH=4, GEGLU FI=2730)
// fp32 residual stream; bf16 MFMA 16x16x32 for all matmuls; flash attention.

#define DEV_INLINE __device__ __forceinline__

typedef short bf16x8 __attribute__((ext_vector_type(8)));
typedef float f32x4 __attribute__((ext_vector_type(4)));

constexpr int Bsz = 4, Nseq = 1024, Dm = 1024, Hh = 16, DH = 64, NDEPTH = 4;
constexpr int FI = 2730;        // GEGLU inner dim
constexpr int FI_PAD = 2752;    // K padded to /32 (zero-filled)
constexpr int FI_TILE = 2816;   // weight rows padded to /128
constexpr int ROWS = Bsz * Nseq; // 4096
constexpr float EPSR = 1.1920929e-07f;

DEV_INLINE float bf2f(unsigned short u) {
  unsigned int x = ((unsigned int)u) << 16;
  float f; __builtin_memcpy(&f, &x, 4); return f;
}
DEV_INLINE unsigned short f2bf(float f) {
  unsigned int x; __builtin_memcpy(&x, &f, 4);
  unsigned int r = x + 0x7fffu + ((x >> 16) & 1u);  // RNE
  return (unsigned short)(r >> 16);
}

// ---------------- weight fp32 -> bf16 (with zero padding) ----------------
__global__ __launch_bounds__(256)
void convf2b(const float* __restrict__ src, unsigned short* __restrict__ dst,
             int src_rows, int src_cols, int dst_cols) {
  const int r = blockIdx.y;
  const int c = blockIdx.x * 256 + threadIdx.x;
  if (c >= dst_cols) return;
  float v = (r < src_rows && c < src_cols) ? src[(size_t)r * src_cols + c] : 0.0f;
  dst[(size_t)r * dst_cols + c] = f2bf(v);
}

// ---------------- rope cos/sin tables ----------------
__global__ __launch_bounds__(256)
void rope_tables(float* __restrict__ cost, float* __restrict__ sint) {
  int idx = blockIdx.x * 256 + threadIdx.x;
  if (idx >= Nseq * 32) return;
  int n = idx >> 5, p = idx & 31;
  float freq = powf(10000.0f, -(float)(2 * p) * (1.0f / 64.0f));
  float ang = (float)n * freq;
  cost[idx] = cosf(ang);
  sint[idx] = sinf(ang);
}

// ---------------- RMSNorm variants ----------------
__global__ __launch_bounds__(256)
void rms_one(const float* __restrict__ x, const float* __restrict__ w,
             unsigned short* __restrict__ out) {
  __shared__ float sred[4];
  const int row = blockIdx.x, tid = threadIdx.x;
  const float4 v = ((const float4*)(x + (size_t)row * Dm))[tid];
  float ss = v.x * v.x + v.y * v.y + v.z * v.z + v.w * v.w;
#pragma unroll
  for (int o = 32; o >= 1; o >>= 1) ss += __shfl_xor(ss, o, 64);
  if ((tid & 63) == 0) sred[tid >> 6] = ss;
  __syncthreads();
  float rs = rsqrtf((sred[0] + sred[1] + sred[2] + sred[3]) * (1.0f / Dm) + EPSR);
  const float4 wv = ((const float4*)w)[tid];
  alignas(8) unsigned short o4[4] = { f2bf(v.x * rs * wv.x), f2bf(v.y * rs * wv.y),
                                      f2bf(v.z * rs * wv.z), f2bf(v.w * rs * wv.w) };
  *(uint2*)&out[(size_t)row * Dm + tid * 4] = *(const uint2*)o4;
}

__global__ __launch_bounds__(256)
void rms_ff(const float* __restrict__ x, const float* __restrict__ w1,
            const float* __restrict__ w2, unsigned short* __restrict__ out) {
  __shared__ float sred[4];
  const int row = blockIdx.x, tid = threadIdx.x;
  const float4 v = ((const float4*)(x + (size_t)row * Dm))[tid];
  const float4 w1v = ((const float4*)w1)[tid];
  const float4 w2v = ((const float4*)w2)[tid];
  float ss = v.x * v.x + v.y * v.y + v.z * v.z + v.w * v.w;
#pragma unroll
  for (int o = 32; o >= 1; o >>= 1) ss += __shfl_xor(ss, o, 64);
  if ((tid & 63) == 0) sred[tid >> 6] = ss;
  __syncthreads();
  float rs1 = rsqrtf((sred[0] + sred[1] + sred[2] + sred[3]) * (1.0f / Dm) + EPSR);
  float t0 = v.x * rs1 * w1v.x, t1 = v.y * rs1 * w1v.y;
  float t2 = v.z * rs1 * w1v.z, t3 = v.w * rs1 * w1v.w;
  float ss2 = t0 * t0 + t1 * t1 + t2 * t2 + t3 * t3;
#pragma unroll
  for (int o = 32; o >= 1; o >>= 1) ss2 += __shfl_xor(ss2, o, 64);
  __syncthreads();   // protect sred reuse
  if ((tid & 63) == 0) sred[tid >> 6] = ss2;
  __syncthreads();
  float rs2 = rsqrtf((sred[0] + sred[1] + sred[2] + sred[3]) * (1.0f / Dm) + EPSR);
  alignas(8) unsigned short o4[4] = { f2bf(t0 * rs2 * w2v.x), f2bf(t1 * rs2 * w2v.y),
                                      f2bf(t2 * rs2 * w2v.z), f2bf(t3 * rs2 * w2v.w) };
  *(uint2*)&out[(size_t)row * Dm + tid * 4] = *(const uint2*)o4;
}

__global__ __launch_bounds__(256)
void rms_final(const float* __restrict__ x, const float* __restrict__ w,
               float* __restrict__ out) {
  __shared__ float sred[4];
  const int row = blockIdx.x, tid = threadIdx.x;
  const float4 v = ((const float4*)(x + (size_t)row * Dm))[tid];
  float ss = v.x * v.x + v.y * v.y + v.z * v.z + v.w * v.w;
#pragma unroll
  for (int o = 32; o >= 1; o >>= 1) ss += __shfl_xor(ss, o, 64);
  if ((tid & 63) == 0) sred[tid >> 6] = ss;
  __syncthreads();
  float rs = rsqrtf((sred[0] + sred[1] + sred[2] + sred[3]) * (1.0f / Dm) + EPSR);
  const float4 wv = ((const float4*)w)[tid];
  float4 o;
  o.x = v.x * rs * wv.x; o.y = v.y * rs * wv.y;
  o.z = v.z * rs * wv.z; o.w = v.w * rs * wv.w;
  ((float4*)(out + (size_t)row * Dm))[tid] = o;
}

// ---------------- NT GEMM: C[M,N] = A[M,K] * Bw[N,K]^T, fused epilogues ----------------
// MODE: 0=bf16 store, 1=sigmoid->f32, 2=f32 residual(+bias), 3=gelu(x+bias)->bf16(pad0),
//       4=(x+bias)*existing->bf16(pad0)
template <int MODE>
__global__ __launch_bounds__(256)
void gemm_nt(const unsigned short* __restrict__ A,
             const unsigned short* __restrict__ Bw,
             void* __restrict__ Cout,
             const float* __restrict__ bias,
             const float* __restrict__ resid,
             int K, int ldc, int n_actual, int n_store) {
  __shared__ unsigned short As[128][40];
  __shared__ unsigned short Bs[128][40];
  const int tid = threadIdx.x;
  const int m0 = blockIdx.x * 128;
  const int n0 = blockIdx.y * 128;
  const int w = tid >> 6, l = tid & 63;
  const int wm = (w >> 1) * 64, wn = (w & 1) * 64;
  const int lr = l & 15, lg = l >> 4;
  const int lk = lg * 8;
  f32x4 acc[4][4] = {};
  const int nk = K >> 5;
  for (int kt = 0; kt < nk; ++kt) {
    const int k0 = kt << 5;
    __syncthreads();
#pragma unroll
    for (int p = 0; p < 2; ++p) {
      int c = tid + p * 256;
      int r = c >> 2, cg = (c & 3) << 3;
      *(uint4*)&As[r][cg] = *(const uint4*)&A[(size_t)(m0 + r) * K + k0 + cg];
      *(uint4*)&Bs[r][cg] = *(const uint4*)&Bw[(size_t)(n0 + r) * K + k0 + cg];
    }
    __syncthreads();
    bf16x8 af[4], bfr[4];
#pragma unroll
    for (int i = 0; i < 4; ++i) af[i] = *(const bf16x8*)&As[wm + i * 16 + lr][lk];
#pragma unroll
    for (int i = 0; i < 4; ++i) bfr[i] = *(const bf16x8*)&Bs[wn + i * 16 + lr][lk];
#pragma unroll
    for (int i = 0; i < 4; ++i)
#pragma unroll
      for (int j = 0; j < 4; ++j)
        acc[i][j] = __builtin_amdgcn_mfma_f32_16x16x32_bf16(af[i], bfr[j], acc[i][j], 0, 0, 0);
  }
  // epilogue: D row = (lane>>4)*4 + r, col = lane&15 (m89-verified layout)
#pragma unroll
  for (int i = 0; i < 4; ++i) {
    const int rowb = m0 + wm + i * 16 + lg * 4;
#pragma unroll
    for (int j = 0; j < 4; ++j) {
      const int col = n0 + wn + j * 16 + lr;
#pragma unroll
      for (int r = 0; r < 4; ++r) {
        const float val = acc[i][j][r];
        const int rr = rowb + r;
        if constexpr (MODE == 0) {
          ((unsigned short*)Cout)[(size_t)rr * ldc + col] = f2bf(val);
        } else if constexpr (MODE == 1) {
          if (col < n_store)
            ((float*)Cout)[(size_t)rr * ldc + col] = 1.0f / (1.0f + expf(-val));
        } else if constexpr (MODE == 2) {
          const float bv = bias ? bias[col] : 0.0f;
          ((float*)Cout)[(size_t)rr * ldc + col] =
              resid[(size_t)rr * ldc + col] + val + bv;
        } else if constexpr (MODE == 3) {
          if (col < n_store) {
            float v = val + bias[col];
            float g = (col < n_actual)
                          ? 0.5f * v * (1.0f + erff(v * 0.70710678118654752f))
                          : 0.0f;
            ((unsigned short*)Cout)[(size_t)rr * ldc + col] = f2bf(g);
          }
        } else {  // MODE 4
          if (col < n_store) {
            float v = val + bias[col];
            float prev = bf2f(((unsigned short*)Cout)[(size_t)rr * ldc + col]);
            float o = (col < n_actual) ? v * prev : 0.0f;
            ((unsigned short*)Cout)[(size_t)rr * ldc + col] = f2bf(o);
          }
        }
      }
    }
  }
}

// ---------------- RoPE on q,k (q also * DH^-0.5) ----------------
__global__ __launch_bounds__(256)
void rope_qk(const unsigned short* __restrict__ qkv_lin,
             const float* __restrict__ cost, const float* __restrict__ sint,
             unsigned short* __restrict__ qb, unsigned short* __restrict__ kb) {
  const int nt = blockIdx.x, bh = blockIdx.y;
  const int b = bh >> 4, h = bh & 15;
  const int tid = threadIdx.x;
  const int pi = tid & 31, r0 = tid >> 5;
  const float scale = 0.125f;
#pragma unroll
  for (int j = 0; j < 8; ++j) {
    const int n = nt * 64 + r0 + j * 8;
    const int nf = b * Nseq + n;
    const float c = cost[n * 32 + pi], s = sint[n * 32 + pi];
    const unsigned short* qp = &qkv_lin[(size_t)nf * 3072 + h * 64 + pi * 2];
    float q0 = bf2f(qp[0]), q1 = bf2f(qp[1]);
    alignas(4) unsigned short oq[2];
    oq[0] = f2bf((q0 * c - q1 * s) * scale);
    oq[1] = f2bf((q1 * c + q0 * s) * scale);
    *(unsigned int*)&qb[((size_t)bh * Nseq + n) * 64 + pi * 2] = *(const unsigned int*)oq;
    const unsigned short* kp = &qkv_lin[(size_t)nf * 3072 + 1024 + h * 64 + pi * 2];
    float k0 = bf2f(kp[0]), k1 = bf2f(kp[1]);
    alignas(4) unsigned short ok[2];
    ok[0] = f2bf(k0 * c - k1 * s);
    ok[1] = f2bf(k1 * c + k0 * s);
    *(unsigned int*)&kb[((size_t)bh * Nseq + n) * 64 + pi * 2] = *(const unsigned int*)ok;
  }
}

// ---------------- v: value-residual lerp + transpose-pack (and save vres @layer0) -------
__global__ __launch_bounds__(256)
void v_mix_pack(const unsigned short* __restrict__ qkv_lin,
                const float* __restrict__ gm,
                unsigned short* __restrict__ vres,
                unsigned short* __restrict__ vtb, int layer) {
  __shared__ unsigned short T[64][72];
  const int nt = blockIdx.x, bh = blockIdx.y;
  const int b = bh >> 4, h = bh & 15;
  const int tid = threadIdx.x;
#pragma unroll
  for (int p = 0; p < 2; ++p) {
    int c = tid + p * 256;
    int nl = c >> 3, cg = (c & 7) << 3;
    int n = nt * 64 + nl, nf = b * Nseq + n;
    uint4 vv = *(const uint4*)&qkv_lin[(size_t)nf * 3072 + 2048 + h * 64 + cg];
    if (layer == 0) {
      *(uint4*)&vres[((size_t)bh * Nseq + n) * 64 + cg] = vv;
      *(uint4*)&T[nl][cg] = vv;
    } else {
      alignas(16) unsigned short ve[8]; *(uint4*)ve = vv;
      uint4 rv = *(const uint4*)&vres[((size_t)bh * Nseq + n) * 64 + cg];
      alignas(16) unsigned short re[8]; *(uint4*)re = rv;
      const float mix = gm[(size_t)nf * 32 + 16 + h];
      alignas(16) unsigned short oe[8];
#pragma unroll
      for (int j = 0; j < 8; ++j) {
        float v = bf2f(ve[j]), rr = bf2f(re[j]);
        oe[j] = f2bf(v + mix * (rr - v));
      }
      *(uint4*)&T[nl][cg] = *(const uint4*)oe;
    }
  }
  __syncthreads();
#pragma unroll
  for (int p = 0; p < 2; ++p) {
    int c = tid + p * 256;
    int d = c >> 3, ng = (c & 7) << 3;
    alignas(16) unsigned short oe[8];
#pragma unroll
    for (int j = 0; j < 8; ++j) oe[j] = T[ng + j][d];
    *(uint4*)&vtb[(size_t)bh * 65536 + (size_t)d * Nseq + nt * 64 + ng] = *(const uint4*)oe;
  }
}

// ---------------- causal flash attention + gate + head-merge ----------------
__global__ __launch_bounds__(256)
void attn_fwd(const unsigned short* __restrict__ qb,
              const unsigned short* __restrict__ kb,
              const unsigned short* __restrict__ vtb,
              const float* __restrict__ gm,
              unsigned short* __restrict__ attn_out) {
  __shared__ unsigned short Ks[64][72];
  __shared__ unsigned short Vs[64][72];   // V^T: [dh][key]
  __shared__ unsigned short Ps[4][16][72];
  const int qt = blockIdx.x;
  const int bh = blockIdx.y;
  const int b = bh >> 4, h = bh & 15;
  const int tid = threadIdx.x;
  const int w = tid >> 6, l = tid & 63;
  const int lr = l & 15, lg = l >> 4;
  const int q0w = qt * 64 + w * 16;
  const size_t head = (size_t)bh * Nseq * DH;

  bf16x8 aq[2];
#pragma unroll
  for (int ks = 0; ks < 2; ++ks)
    aq[ks] = *(const bf16x8*)&qb[head + (size_t)(q0w + lr) * DH + ks * 32 + lg * 8];

  float mrow[4] = {-INFINITY, -INFINITY, -INFINITY, -INFINITY};
  float lsum[4] = {0.f, 0.f, 0.f, 0.f};
  f32x4 acco[4] = {};

  for (int kt = 0; kt <= qt; ++kt) {
    const int kv0 = kt * 64;
    __syncthreads();
#pragma unroll
    for (int p = 0; p < 2; ++p) {
      int c = tid + p * 256;
      int r = c >> 3, cg = (c & 7) << 3;
      *(uint4*)&Ks[r][cg] = *(const uint4*)&kb[head + (size_t)(kv0 + r) * DH + cg];
      *(uint4*)&Vs[r][cg] = *(const uint4*)&vtb[head + (size_t)r * Nseq + kv0 + cg];
    }
    __syncthreads();
    f32x4 s[4];
#pragma unroll
    for (int t = 0; t < 4; ++t) {
      bf16x8 bk0 = *(const bf16x8*)&Ks[t * 16 + lr][lg * 8];
      bf16x8 bk1 = *(const bf16x8*)&Ks[t * 16 + lr][32 + lg * 8];
      f32x4 z = {};
      z = __builtin_amdgcn_mfma_f32_16x16x32_bf16(aq[0], bk0, z, 0, 0, 0);
      z = __builtin_amdgcn_mfma_f32_16x16x32_bf16(aq[1], bk1, z, 0, 0, 0);
      s[t] = z;
    }
#pragma unroll
    for (int r = 0; r < 4; ++r) {
      const int qr = q0w + lg * 4 + r;
      float mx = -1e30f;
#pragma unroll
      for (int t = 0; t < 4; ++t) {
        const int key = kv0 + t * 16 + lr;
        float sv = (key > qr) ? -1e30f : s[t][r];
        s[t][r] = sv;
        mx = fmaxf(mx, sv);
      }
      mx = fmaxf(mx, __shfl_xor(mx, 1, 64));
      mx = fmaxf(mx, __shfl_xor(mx, 2, 64));
      mx = fmaxf(mx, __shfl_xor(mx, 4, 64));
      mx = fmaxf(mx, __shfl_xor(mx, 8, 64));
      const float mn = fmaxf(mrow[r], mx);
      const float alpha = expf(mrow[r] - mn);
      mrow[r] = mn;
      float rs = 0.f;
#pragma unroll
      for (int t = 0; t < 4; ++t) {
        float pv = expf(s[t][r] - mn);
        s[t][r] = pv;
        rs += pv;
      }
      rs += __shfl_xor(rs, 1, 64);
      rs += __shfl_xor(rs, 2, 64);
      rs += __shfl_xor(rs, 4, 64);
      rs += __shfl_xor(rs, 8, 64);
      lsum[r] = lsum[r] * alpha + rs;
#pragma unroll
      for (int dt = 0; dt < 4; ++dt) acco[dt][r] *= alpha;
    }
#pragma unroll
    for (int t = 0; t < 4; ++t)
#pragma unroll
      for (int r = 0; r < 4; ++r)
        Ps[w][lg * 4 + r][t * 16 + lr] = f2bf(s[t][r]);
#pragma unroll
    for (int ks = 0; ks < 2; ++ks) {
      bf16x8 ap = *(const bf16x8*)&Ps[w][lr][ks * 32 + lg * 8];
#pragma unroll
      for (int dt = 0; dt < 4; ++dt) {
        bf16x8 bv = *(const bf16x8*)&Vs[dt * 16 + lr][ks * 32 + lg * 8];
        acco[dt] = __builtin_amdgcn_mfma_f32_16x16x32_bf16(ap, bv, acco[dt], 0, 0, 0);
      }
    }
  }
#pragma unroll
  for (int r = 0; r < 4; ++r) {
    const int qr = q0w + lg * 4 + r;
    const int nf = b * Nseq + qr;
    const float gate = gm[(size_t)nf * 32 + h];
    const float inv = 1.0f / lsum[r];
#pragma unroll
    for (int dt = 0; dt < 4; ++dt)
      attn_out[(size_t)nf * Dm + h * DH + dt * 16 + lr] = f2bf(acco[dt][r] * inv * gate);
  }
}

// ---------------- host launch ----------------
extern "C" void kernel_launch(void* const* d_in, const int* in_sizes, int n_in,
                              void* d_out, int out_size, void* d_ws, size_t ws_size,
                              hipStream_t stream) {
  const float* x_in  = (const float*)d_in[0];
  const float* naw   = (const float*)d_in[1];
  const float* wq    = (const float*)d_in[2];
  const float* wkv   = (const float*)d_in[3];
  const float* wo    = (const float*)d_in[4];
  const float* wg    = (const float*)d_in[5];
  const float* wmix  = (const float*)d_in[6];
  const float* nfw   = (const float*)d_in[7];
  const float* ffw   = (const float*)d_in[8];
  const float* w_in  = (const float*)d_in[9];
  const float* b_in  = (const float*)d_in[10];
  const float* w_out = (const float*)d_in[11];
  const float* b_out = (const float*)d_in[12];
  const float* fnw   = (const float*)d_in[13];

  uint8_t* ws = (uint8_t*)d_ws;
  size_t off = 0;
  auto alloc = [&](size_t bytes) -> void* {
    void* p = ws + off;
    off += (bytes + 255) & ~(size_t)255;
    return p;
  };
  float*          x_res    = (float*)alloc((size_t)ROWS * Dm * 4);
  unsigned short* h        = (unsigned short*)alloc((size_t)ROWS * Dm * 2);
  unsigned short* qkv_lin  = (unsigned short*)alloc((size_t)ROWS * 3072 * 2);
  float*          gm       = (float*)alloc((size_t)ROWS * 32 * 4);
  unsigned short* qb       = (unsigned short*)alloc((size_t)64 * Nseq * DH * 2);
  unsigned short* kb       = (unsigned short*)alloc((size_t)64 * Nseq * DH * 2);
  unsigned short* vtb      = (unsigned short*)alloc((size_t)64 * Nseq * DH * 2);
  unsigned short* vres     = (unsigned short*)alloc((size_t)64 * Nseq * DH * 2);
  unsigned short* attn     = (unsigned short*)alloc((size_t)ROWS * Dm * 2);
  float*          cost     = (float*)alloc((size_t)Nseq * 32 * 4);
  float*          sint     = (float*)alloc((size_t)Nseq * 32 * 4);
  unsigned short* wqkv_bf  = (unsigned short*)alloc((size_t)3072 * 1024 * 2);
  unsigned short* wo_bf    = (unsigned short*)alloc((size_t)1024 * 1024 * 2);
  unsigned short* wgm_bf   = (unsigned short*)alloc((size_t)128 * 1024 * 2);
  unsigned short* wina_bf  = (unsigned short*)alloc((size_t)FI_TILE * 1024 * 2);
  unsigned short* wingt_bf = (unsigned short*)alloc((size_t)FI_TILE * 1024 * 2);
  unsigned short* wout_bf  = (unsigned short*)alloc((size_t)1024 * FI_PAD * 2);
  unsigned short* u = qkv_lin;  // alias: qkv scratch dead before FF uses u

  hipMemcpyAsync(x_res, x_in, (size_t)ROWS * Dm * 4, hipMemcpyDeviceToDevice, stream);
  rope_tables<<<128, 256, 0, stream>>>(cost, sint);

  for (int i = 0; i < NDEPTH; ++i) {
    convf2b<<<dim3(4, 1024), 256, 0, stream>>>(wq + (size_t)i * 1024 * 1024, wqkv_bf, 1024, 1024, 1024);
    convf2b<<<dim3(4, 2048), 256, 0, stream>>>(wkv + (size_t)i * 2048 * 1024, wqkv_bf + (size_t)1024 * 1024, 2048, 1024, 1024);
    convf2b<<<dim3(4, 1024), 256, 0, stream>>>(wo + (size_t)i * 1024 * 1024, wo_bf, 1024, 1024, 1024);
    convf2b<<<dim3(4, 16), 256, 0, stream>>>(wg + (size_t)i * 16 * 1024, wgm_bf, 16, 1024, 1024);
    convf2b<<<dim3(4, 16), 256, 0, stream>>>(wmix + (size_t)i * 16 * 1024, wgm_bf + 16 * 1024, 16, 1024, 1024);
    convf2b<<<dim3(4, 96), 256, 0, stream>>>(wg, wgm_bf + 32 * 1024, 0, 1024, 1024);  // zero rows 32..127
    convf2b<<<dim3(4, FI_TILE), 256, 0, stream>>>(w_in + (size_t)i * 2 * FI * 1024, wina_bf, FI, 1024, 1024);
    convf2b<<<dim3(4, FI_TILE), 256, 0, stream>>>(w_in + (size_t)i * 2 * FI * 1024 + (size_t)FI * 1024, wingt_bf, FI, 1024, 1024);
    convf2b<<<dim3(11, 1024), 256, 0, stream>>>(w_out + (size_t)i * 1024 * FI, wout_bf, 1024, FI, FI_PAD);

    rms_one<<<ROWS, 256, 0, stream>>>(x_res, naw + i * 1024, h);
    gemm_nt<0><<<dim3(32, 24), 256, 0, stream>>>(h, wqkv_bf, qkv_lin, nullptr, nullptr, 1024, 3072, 3072, 3072);
    gemm_nt<1><<<dim3(32, 1), 256, 0, stream>>>(h, wgm_bf, gm, nullptr, nullptr, 1024, 32, 32, 32);
    rope_qk<<<dim3(16, 64), 256, 0, stream>>>(qkv_lin, cost, sint, qb, kb);
    v_mix_pack<<<dim3(16, 64), 256, 0, stream>>>(qkv_lin, gm, vres, vtb, i);
    attn_fwd<<<dim3(16, 64), 256, 0, stream>>>(qb, kb, vtb, gm, attn);
    gemm_nt<2><<<dim3(32, 8), 256, 0, stream>>>(attn, wo_bf, x_res, nullptr, x_res, 1024, 1024, 1024, 1024);
    rms_ff<<<ROWS, 256, 0, stream>>>(x_res, nfw + i * 1024, ffw + i * 1024, h);
    gemm_nt<3><<<dim3(32, 22), 256, 0, stream>>>(h, wingt_bf, u, b_in + (size_t)i * 2 * FI + FI, nullptr, 1024, FI_PAD, FI, FI_PAD);
    gemm_nt<4><<<dim3(32, 22), 256, 0, stream>>>(h, wina_bf, u, b_in + (size_t)i * 2 * FI, nullptr, 1024, FI_PAD, FI, FI_PAD);
    gemm_nt<2><<<dim3(32, 8), 256, 0, stream>>>(u, wout_bf, x_res, b_out + i * 1024, x_res, FI_PAD, 1024, 1024, 1024);
  }
  rms_final<<<ROWS, 256, 0, stream>>>(x_res, fnw, (float*)d_out);
}

// Round 3
// 1723.325 us; speedup vs baseline: 1.0422x; 1.0422x over previous
//
#include <hip/hip_runtime.h>
#include <cstdint>
#include <cstddef>

// TransformerXL forward (B=4,N=1024,D=1024,H=16,DH=64,DEPTH=4, GEGLU FI=2730)
// fp32 residual stream; bf16 MFMA 16x16x32 for all matmuls; flash attention.
// R3: R2 (global_load_lds GEMM staging + barrier-free attn) with Ps[.][.][72]
//     fix — R2's Ps[..][40] was 24 elements too narrow (P tile is 64 wide),
//     causing cross-wave LDS corruption.

#define DEV_INLINE __device__ __forceinline__

typedef short bf16x8 __attribute__((ext_vector_type(8)));
typedef float f32x4 __attribute__((ext_vector_type(4)));

constexpr int Bsz = 4, Nseq = 1024, Dm = 1024, Hh = 16, DH = 64, NDEPTH = 4;
constexpr int FI = 2730;        // GEGLU inner dim
constexpr int FI_PAD = 2752;    // K padded to /32 (zero-filled)
constexpr int FI_TILE = 2816;   // weight rows padded to /128
constexpr int ROWS = Bsz * Nseq; // 4096
constexpr float EPSR = 1.1920929e-07f;

DEV_INLINE float bf2f(unsigned short u) {
  unsigned int x = ((unsigned int)u) << 16;
  float f; __builtin_memcpy(&f, &x, 4); return f;
}
DEV_INLINE unsigned short f2bf(float f) {
  unsigned int x; __builtin_memcpy(&x, &f, 4);
  unsigned int r = x + 0x7fffu + ((x >> 16) & 1u);  // RNE
  return (unsigned short)(r >> 16);
}

using gptr_t = const __attribute__((address_space(1))) void*;
using lptr_t = __attribute__((address_space(3))) void*;
DEV_INLINE void gl_lds16(const void* g, void* l) {
  // async global->LDS, 16B/lane; LDS dest = wave-uniform base + lane*16
  __builtin_amdgcn_global_load_lds((gptr_t)g, (lptr_t)l, 16, 0, 0);
}

// ---------------- weight fp32 -> bf16 (with zero padding) ----------------
__global__ __launch_bounds__(256)
void convf2b(const float* __restrict__ src, unsigned short* __restrict__ dst,
             int src_rows, int src_cols, int dst_cols) {
  const int r = blockIdx.y;
  const int c = blockIdx.x * 256 + threadIdx.x;
  if (c >= dst_cols) return;
  float v = (r < src_rows && c < src_cols) ? src[(size_t)r * src_cols + c] : 0.0f;
  dst[(size_t)r * dst_cols + c] = f2bf(v);
}

// ---------------- rope cos/sin tables ----------------
__global__ __launch_bounds__(256)
void rope_tables(float* __restrict__ cost, float* __restrict__ sint) {
  int idx = blockIdx.x * 256 + threadIdx.x;
  if (idx >= Nseq * 32) return;
  int n = idx >> 5, p = idx & 31;
  float freq = powf(10000.0f, -(float)(2 * p) * (1.0f / 64.0f));
  float ang = (float)n * freq;
  cost[idx] = cosf(ang);
  sint[idx] = sinf(ang);
}

// ---------------- RMSNorm variants ----------------
__global__ __launch_bounds__(256)
void rms_one(const float* __restrict__ x, const float* __restrict__ w,
             unsigned short* __restrict__ out) {
  __shared__ float sred[4];
  const int row = blockIdx.x, tid = threadIdx.x;
  const float4 v = ((const float4*)(x + (size_t)row * Dm))[tid];
  float ss = v.x * v.x + v.y * v.y + v.z * v.z + v.w * v.w;
#pragma unroll
  for (int o = 32; o >= 1; o >>= 1) ss += __shfl_xor(ss, o, 64);
  if ((tid & 63) == 0) sred[tid >> 6] = ss;
  __syncthreads();
  float rs = rsqrtf((sred[0] + sred[1] + sred[2] + sred[3]) * (1.0f / Dm) + EPSR);
  const float4 wv = ((const float4*)w)[tid];
  alignas(8) unsigned short o4[4] = { f2bf(v.x * rs * wv.x), f2bf(v.y * rs * wv.y),
                                      f2bf(v.z * rs * wv.z), f2bf(v.w * rs * wv.w) };
  *(uint2*)&out[(size_t)row * Dm + tid * 4] = *(const uint2*)o4;
}

__global__ __launch_bounds__(256)
void rms_ff(const float* __restrict__ x, const float* __restrict__ w1,
            const float* __restrict__ w2, unsigned short* __restrict__ out) {
  __shared__ float sred[4];
  const int row = blockIdx.x, tid = threadIdx.x;
  const float4 v = ((const float4*)(x + (size_t)row * Dm))[tid];
  const float4 w1v = ((const float4*)w1)[tid];
  const float4 w2v = ((const float4*)w2)[tid];
  float ss = v.x * v.x + v.y * v.y + v.z * v.z + v.w * v.w;
#pragma unroll
  for (int o = 32; o >= 1; o >>= 1) ss += __shfl_xor(ss, o, 64);
  if ((tid & 63) == 0) sred[tid >> 6] = ss;
  __syncthreads();
  float rs1 = rsqrtf((sred[0] + sred[1] + sred[2] + sred[3]) * (1.0f / Dm) + EPSR);
  float t0 = v.x * rs1 * w1v.x, t1 = v.y * rs1 * w1v.y;
  float t2 = v.z * rs1 * w1v.z, t3 = v.w * rs1 * w1v.w;
  float ss2 = t0 * t0 + t1 * t1 + t2 * t2 + t3 * t3;
#pragma unroll
  for (int o = 32; o >= 1; o >>= 1) ss2 += __shfl_xor(ss2, o, 64);
  __syncthreads();   // protect sred reuse
  if ((tid & 63) == 0) sred[tid >> 6] = ss2;
  __syncthreads();
  float rs2 = rsqrtf((sred[0] + sred[1] + sred[2] + sred[3]) * (1.0f / Dm) + EPSR);
  alignas(8) unsigned short o4[4] = { f2bf(t0 * rs2 * w2v.x), f2bf(t1 * rs2 * w2v.y),
                                      f2bf(t2 * rs2 * w2v.z), f2bf(t3 * rs2 * w2v.w) };
  *(uint2*)&out[(size_t)row * Dm + tid * 4] = *(const uint2*)o4;
}

__global__ __launch_bounds__(256)
void rms_final(const float* __restrict__ x, const float* __restrict__ w,
               float* __restrict__ out) {
  __shared__ float sred[4];
  const int row = blockIdx.x, tid = threadIdx.x;
  const float4 v = ((const float4*)(x + (size_t)row * Dm))[tid];
  float ss = v.x * v.x + v.y * v.y + v.z * v.z + v.w * v.w;
#pragma unroll
  for (int o = 32; o >= 1; o >>= 1) ss += __shfl_xor(ss, o, 64);
  if ((tid & 63) == 0) sred[tid >> 6] = ss;
  __syncthreads();
  float rs = rsqrtf((sred[0] + sred[1] + sred[2] + sred[3]) * (1.0f / Dm) + EPSR);
  const float4 wv = ((const float4*)w)[tid];
  float4 o;
  o.x = v.x * rs * wv.x; o.y = v.y * rs * wv.y;
  o.z = v.z * rs * wv.z; o.w = v.w * rs * wv.w;
  ((float4*)(out + (size_t)row * Dm))[tid] = o;
}

// ---------------- NT GEMM: C[M,N] = A[M,K] * Bw[N,K]^T, fused epilogues ----------------
// m97 structure: 128x128 tile, BK=32, global_load_lds(16B) staging, linear LDS.
// MODE: 0=bf16 store, 1=sigmoid->f32, 2=f32 residual(+bias), 3=gelu(x+bias)->bf16(pad0),
//       4=(x+bias)*existing->bf16(pad0)
template <int MODE>
__global__ __launch_bounds__(256)
void gemm_nt(const unsigned short* __restrict__ A,
             const unsigned short* __restrict__ Bw,
             void* __restrict__ Cout,
             const float* __restrict__ bias,
             const float* __restrict__ resid,
             int K, int ldc, int n_actual, int n_store) {
  __shared__ unsigned short As[128 * 32];
  __shared__ unsigned short Bs[128 * 32];
  const int tid = threadIdx.x;
  const int m0 = blockIdx.x * 128;
  const int n0 = blockIdx.y * 128;
  const int w = tid >> 6, l = tid & 63;
  const int wm = (w >> 1) * 64, wn = (w & 1) * 64;
  const int lr = l & 15, lg = l >> 4;
  const int lk = lg * 8;
  // staging geometry: lane of wave w writes LDS element tid*8 = row*32+col,
  // matching per-lane global src A[(m0 + tid/4)*K + (tid&3)*8]
  const int r0 = tid >> 2, c0 = (tid & 3) << 3;
  unsigned short* lA0 = &As[w * 512];
  unsigned short* lA1 = &As[2048 + w * 512];
  unsigned short* lB0 = &Bs[w * 512];
  unsigned short* lB1 = &Bs[2048 + w * 512];
  const unsigned short* gA0 = &A[(size_t)(m0 + r0) * K + c0];
  const unsigned short* gA1 = &A[(size_t)(m0 + r0 + 64) * K + c0];
  const unsigned short* gB0 = &Bw[(size_t)(n0 + r0) * K + c0];
  const unsigned short* gB1 = &Bw[(size_t)(n0 + r0 + 64) * K + c0];
  f32x4 acc[4][4] = {};
  const int nk = K >> 5;
  for (int kt = 0; kt < nk; ++kt) {
    __syncthreads();   // previous tile fully consumed
    gl_lds16(gA0, lA0); gl_lds16(gA1, lA1);
    gl_lds16(gB0, lB0); gl_lds16(gB1, lB1);
    gA0 += 32; gA1 += 32; gB0 += 32; gB1 += 32;
    __syncthreads();   // vmcnt(0) drain -> tile ready
    bf16x8 af[4], bfr[4];
#pragma unroll
    for (int i = 0; i < 4; ++i) af[i] = *(const bf16x8*)&As[(wm + i * 16 + lr) * 32 + lk];
#pragma unroll
    for (int i = 0; i < 4; ++i) bfr[i] = *(const bf16x8*)&Bs[(wn + i * 16 + lr) * 32 + lk];
#pragma unroll
    for (int i = 0; i < 4; ++i)
#pragma unroll
      for (int j = 0; j < 4; ++j)
        acc[i][j] = __builtin_amdgcn_mfma_f32_16x16x32_bf16(af[i], bfr[j], acc[i][j], 0, 0, 0);
  }
  // epilogue: D row = (lane>>4)*4 + r, col = lane&15 (m89-verified layout)
#pragma unroll
  for (int i = 0; i < 4; ++i) {
    const int rowb = m0 + wm + i * 16 + lg * 4;
#pragma unroll
    for (int j = 0; j < 4; ++j) {
      const int col = n0 + wn + j * 16 + lr;
#pragma unroll
      for (int r = 0; r < 4; ++r) {
        const float val = acc[i][j][r];
        const int rr = rowb + r;
        if constexpr (MODE == 0) {
          ((unsigned short*)Cout)[(size_t)rr * ldc + col] = f2bf(val);
        } else if constexpr (MODE == 1) {
          if (col < n_store)
            ((float*)Cout)[(size_t)rr * ldc + col] = 1.0f / (1.0f + __expf(-val));
        } else if constexpr (MODE == 2) {
          const float bv = bias ? bias[col] : 0.0f;
          ((float*)Cout)[(size_t)rr * ldc + col] =
              resid[(size_t)rr * ldc + col] + val + bv;
        } else if constexpr (MODE == 3) {
          if (col < n_store) {
            float v = val + bias[col];
            float g = (col < n_actual)
                          ? 0.5f * v * (1.0f + erff(v * 0.70710678118654752f))
                          : 0.0f;
            ((unsigned short*)Cout)[(size_t)rr * ldc + col] = f2bf(g);
          }
        } else {  // MODE 4
          if (col < n_store) {
            float v = val + bias[col];
            float prev = bf2f(((unsigned short*)Cout)[(size_t)rr * ldc + col]);
            float o = (col < n_actual) ? v * prev : 0.0f;
            ((unsigned short*)Cout)[(size_t)rr * ldc + col] = f2bf(o);
          }
        }
      }
    }
  }
}

// ---------------- RoPE on q,k (q also * DH^-0.5) ----------------
__global__ __launch_bounds__(256)
void rope_qk(const unsigned short* __restrict__ qkv_lin,
             const float* __restrict__ cost, const float* __restrict__ sint,
             unsigned short* __restrict__ qb, unsigned short* __restrict__ kb) {
  const int nt = blockIdx.x, bh = blockIdx.y;
  const int b = bh >> 4, h = bh & 15;
  const int tid = threadIdx.x;
  const int pi = tid & 31, r0 = tid >> 5;
  const float scale = 0.125f;
#pragma unroll
  for (int j = 0; j < 8; ++j) {
    const int n = nt * 64 + r0 + j * 8;
    const int nf = b * Nseq + n;
    const float c = cost[n * 32 + pi], s = sint[n * 32 + pi];
    const unsigned short* qp = &qkv_lin[(size_t)nf * 3072 + h * 64 + pi * 2];
    float q0 = bf2f(qp[0]), q1 = bf2f(qp[1]);
    alignas(4) unsigned short oq[2];
    oq[0] = f2bf((q0 * c - q1 * s) * scale);
    oq[1] = f2bf((q1 * c + q0 * s) * scale);
    *(unsigned int*)&qb[((size_t)bh * Nseq + n) * 64 + pi * 2] = *(const unsigned int*)oq;
    const unsigned short* kp = &qkv_lin[(size_t)nf * 3072 + 1024 + h * 64 + pi * 2];
    float k0 = bf2f(kp[0]), k1 = bf2f(kp[1]);
    alignas(4) unsigned short ok[2];
    ok[0] = f2bf(k0 * c - k1 * s);
    ok[1] = f2bf(k1 * c + k0 * s);
    *(unsigned int*)&kb[((size_t)bh * Nseq + n) * 64 + pi * 2] = *(const unsigned int*)ok;
  }
}

// ---------------- v: value-residual lerp + transpose-pack (and save vres @layer0) -------
__global__ __launch_bounds__(256)
void v_mix_pack(const unsigned short* __restrict__ qkv_lin,
                const float* __restrict__ gm,
                unsigned short* __restrict__ vres,
                unsigned short* __restrict__ vtb, int layer) {
  __shared__ unsigned short T[64][72];
  const int nt = blockIdx.x, bh = blockIdx.y;
  const int b = bh >> 4, h = bh & 15;
  const int tid = threadIdx.x;
#pragma unroll
  for (int p = 0; p < 2; ++p) {
    int c = tid + p * 256;
    int nl = c >> 3, cg = (c & 7) << 3;
    int n = nt * 64 + nl, nf = b * Nseq + n;
    uint4 vv = *(const uint4*)&qkv_lin[(size_t)nf * 3072 + 2048 + h * 64 + cg];
    if (layer == 0) {
      *(uint4*)&vres[((size_t)bh * Nseq + n) * 64 + cg] = vv;
      *(uint4*)&T[nl][cg] = vv;
    } else {
      alignas(16) unsigned short ve[8]; *(uint4*)ve = vv;
      uint4 rv = *(const uint4*)&vres[((size_t)bh * Nseq + n) * 64 + cg];
      alignas(16) unsigned short re[8]; *(uint4*)re = rv;
      const float mix = gm[(size_t)nf * 32 + 16 + h];
      alignas(16) unsigned short oe[8];
#pragma unroll
      for (int j = 0; j < 8; ++j) {
        float v = bf2f(ve[j]), rr = bf2f(re[j]);
        oe[j] = f2bf(v + mix * (rr - v));
      }
      *(uint4*)&T[nl][cg] = *(const uint4*)oe;
    }
  }
  __syncthreads();
#pragma unroll
  for (int p = 0; p < 2; ++p) {
    int c = tid + p * 256;
    int d = c >> 3, ng = (c & 7) << 3;
    alignas(16) unsigned short oe[8];
#pragma unroll
    for (int j = 0; j < 8; ++j) oe[j] = T[ng + j][d];
    *(uint4*)&vtb[(size_t)bh * 65536 + (size_t)d * Nseq + nt * 64 + ng] = *(const uint4*)oe;
  }
}

// ---------------- causal flash attention + gate + head-merge ----------------
// Barrier-free: each wave owns 16 q-rows; K/V^T fragments read directly from
// global (L2-resident, 256KB/head); only per-wave P transpose goes via LDS.
// Block decode: XCD x gets heads [x*8, x*8+8) (2MB < 4MB L2); qt descending.
__global__ __launch_bounds__(256)
void attn_fwd(const unsigned short* __restrict__ qb,
              const unsigned short* __restrict__ kb,
              const unsigned short* __restrict__ vtb,
              const float* __restrict__ gm,
              unsigned short* __restrict__ attn_out) {
  __shared__ unsigned short Ps[4][16][72];   // 64 cols + 8 pad (R2 bug: was 40)
  const int bid = blockIdx.x;
  const int x = bid & 7, rest = bid >> 3;
  const int bh = x * 8 + (rest & 7);
  const int qt = 15 - (rest >> 3);
  const int b = bh >> 4, h = bh & 15;
  const int tid = threadIdx.x;
  const int w = tid >> 6, l = tid & 63;
  const int lr = l & 15, lg = l >> 4;
  const int q0 = qt * 64 + w * 16;           // this wave's q-row base
  const size_t head = (size_t)bh * Nseq * DH;

  bf16x8 aq[2];
  aq[0] = *(const bf16x8*)&qb[head + (size_t)(q0 + lr) * DH + lg * 8];
  aq[1] = *(const bf16x8*)&qb[head + (size_t)(q0 + lr) * DH + 32 + lg * 8];

  float mrow[4] = {-1e30f, -1e30f, -1e30f, -1e30f};
  float lsum[4] = {0.f, 0.f, 0.f, 0.f};
  f32x4 acco[4] = {};

  for (int kt = 0; kt <= qt; ++kt) {
    const int kv0 = kt * 64;
    f32x4 s[4];
#pragma unroll
    for (int t = 0; t < 4; ++t) {
      bf16x8 bk0 = *(const bf16x8*)&kb[head + (size_t)(kv0 + t * 16 + lr) * DH + lg * 8];
      bf16x8 bk1 = *(const bf16x8*)&kb[head + (size_t)(kv0 + t * 16 + lr) * DH + 32 + lg * 8];
      f32x4 z = {};
      z = __builtin_amdgcn_mfma_f32_16x16x32_bf16(aq[0], bk0, z, 0, 0, 0);
      z = __builtin_amdgcn_mfma_f32_16x16x32_bf16(aq[1], bk1, z, 0, 0, 0);
      s[t] = z;
    }
    const bool diag = (kt == qt);
#pragma unroll
    for (int r = 0; r < 4; ++r) {
      const int qr = q0 + lg * 4 + r;
      float mx = -1e30f;
#pragma unroll
      for (int t = 0; t < 4; ++t) {
        float sv = s[t][r];
        if (diag && (kv0 + t * 16 + lr > qr)) sv = -1e30f;
        s[t][r] = sv;
        mx = fmaxf(mx, sv);
      }
      mx = fmaxf(mx, __shfl_xor(mx, 1, 64));
      mx = fmaxf(mx, __shfl_xor(mx, 2, 64));
      mx = fmaxf(mx, __shfl_xor(mx, 4, 64));
      mx = fmaxf(mx, __shfl_xor(mx, 8, 64));
      const float mn = fmaxf(mrow[r], mx);
      const float alpha = __expf(mrow[r] - mn);
      mrow[r] = mn;
      float rs = 0.f;
#pragma unroll
      for (int t = 0; t < 4; ++t) {
        float pv = __expf(s[t][r] - mn);
        s[t][r] = pv;
        rs += pv;
      }
      rs += __shfl_xor(rs, 1, 64);
      rs += __shfl_xor(rs, 2, 64);
      rs += __shfl_xor(rs, 4, 64);
      rs += __shfl_xor(rs, 8, 64);
      lsum[r] = lsum[r] * alpha + rs;
#pragma unroll
      for (int dt = 0; dt < 4; ++dt) acco[dt][r] *= alpha;
    }
#pragma unroll
    for (int t = 0; t < 4; ++t)
#pragma unroll
      for (int r = 0; r < 4; ++r)
        Ps[w][lg * 4 + r][t * 16 + lr] = f2bf(s[t][r]);
#pragma unroll
    for (int ks = 0; ks < 2; ++ks) {
      bf16x8 ap = *(const bf16x8*)&Ps[w][lr][ks * 32 + lg * 8];
#pragma unroll
      for (int dt = 0; dt < 4; ++dt) {
        bf16x8 bv = *(const bf16x8*)&vtb[head + (size_t)(dt * 16 + lr) * Nseq + kv0 + ks * 32 + lg * 8];
        acco[dt] = __builtin_amdgcn_mfma_f32_16x16x32_bf16(ap, bv, acco[dt], 0, 0, 0);
      }
    }
  }
#pragma unroll
  for (int r = 0; r < 4; ++r) {
    const int qr = q0 + lg * 4 + r;
    const int nf = b * Nseq + qr;
    const float gate = gm[(size_t)nf * 32 + h];
    const float inv = 1.0f / lsum[r];
#pragma unroll
    for (int dt = 0; dt < 4; ++dt)
      attn_out[(size_t)nf * Dm + h * DH + dt * 16 + lr] = f2bf(acco[dt][r] * inv * gate);
  }
}

// ---------------- host launch ----------------
extern "C" void kernel_launch(void* const* d_in, const int* in_sizes, int n_in,
                              void* d_out, int out_size, void* d_ws, size_t ws_size,
                              hipStream_t stream) {
  const float* x_in  = (const float*)d_in[0];
  const float* naw   = (const float*)d_in[1];
  const float* wq    = (const float*)d_in[2];
  const float* wkv   = (const float*)d_in[3];
  const float* wo    = (const float*)d_in[4];
  const float* wg    = (const float*)d_in[5];
  const float* wmix  = (const float*)d_in[6];
  const float* nfw   = (const float*)d_in[7];
  const float* ffw   = (const float*)d_in[8];
  const float* w_in  = (const float*)d_in[9];
  const float* b_in  = (const float*)d_in[10];
  const float* w_out = (const float*)d_in[11];
  const float* b_out = (const float*)d_in[12];
  const float* fnw   = (const float*)d_in[13];

  uint8_t* ws = (uint8_t*)d_ws;
  size_t off = 0;
  auto alloc = [&](size_t bytes) -> void* {
    void* p = ws + off;
    off += (bytes + 255) & ~(size_t)255;
    return p;
  };
  float*          x_res    = (float*)alloc((size_t)ROWS * Dm * 4);
  unsigned short* h        = (unsigned short*)alloc((size_t)ROWS * Dm * 2);
  unsigned short* qkv_lin  = (unsigned short*)alloc((size_t)ROWS * 3072 * 2);
  float*          gm       = (float*)alloc((size_t)ROWS * 32 * 4);
  unsigned short* qb       = (unsigned short*)alloc((size_t)64 * Nseq * DH * 2);
  unsigned short* kb       = (unsigned short*)alloc((size_t)64 * Nseq * DH * 2);
  unsigned short* vtb      = (unsigned short*)alloc((size_t)64 * Nseq * DH * 2);
  unsigned short* vres     = (unsigned short*)alloc((size_t)64 * Nseq * DH * 2);
  unsigned short* attn     = (unsigned short*)alloc((size_t)ROWS * Dm * 2);
  float*          cost     = (float*)alloc((size_t)Nseq * 32 * 4);
  float*          sint     = (float*)alloc((size_t)Nseq * 32 * 4);
  unsigned short* wqkv_bf  = (unsigned short*)alloc((size_t)3072 * 1024 * 2);
  unsigned short* wo_bf    = (unsigned short*)alloc((size_t)1024 * 1024 * 2);
  unsigned short* wgm_bf   = (unsigned short*)alloc((size_t)128 * 1024 * 2);
  unsigned short* wina_bf  = (unsigned short*)alloc((size_t)FI_TILE * 1024 * 2);
  unsigned short* wingt_bf = (unsigned short*)alloc((size_t)FI_TILE * 1024 * 2);
  unsigned short* wout_bf  = (unsigned short*)alloc((size_t)1024 * FI_PAD * 2);
  unsigned short* u = qkv_lin;  // alias: qkv scratch dead before FF uses u

  hipMemcpyAsync(x_res, x_in, (size_t)ROWS * Dm * 4, hipMemcpyDeviceToDevice, stream);
  rope_tables<<<128, 256, 0, stream>>>(cost, sint);

  for (int i = 0; i < NDEPTH; ++i) {
    convf2b<<<dim3(4, 1024), 256, 0, stream>>>(wq + (size_t)i * 1024 * 1024, wqkv_bf, 1024, 1024, 1024);
    convf2b<<<dim3(4, 2048), 256, 0, stream>>>(wkv + (size_t)i * 2048 * 1024, wqkv_bf + (size_t)1024 * 1024, 2048, 1024, 1024);
    convf2b<<<dim3(4, 1024), 256, 0, stream>>>(wo + (size_t)i * 1024 * 1024, wo_bf, 1024, 1024, 1024);
    convf2b<<<dim3(4, 16), 256, 0, stream>>>(wg + (size_t)i * 16 * 1024, wgm_bf, 16, 1024, 1024);
    convf2b<<<dim3(4, 16), 256, 0, stream>>>(wmix + (size_t)i * 16 * 1024, wgm_bf + 16 * 1024, 16, 1024, 1024);
    convf2b<<<dim3(4, 96), 256, 0, stream>>>(wg, wgm_bf + 32 * 1024, 0, 1024, 1024);  // zero rows 32..127
    convf2b<<<dim3(4, FI_TILE), 256, 0, stream>>>(w_in + (size_t)i * 2 * FI * 1024, wina_bf, FI, 1024, 1024);
    convf2b<<<dim3(4, FI_TILE), 256, 0, stream>>>(w_in + (size_t)i * 2 * FI * 1024 + (size_t)FI * 1024, wingt_bf, FI, 1024, 1024);
    convf2b<<<dim3(11, 1024), 256, 0, stream>>>(w_out + (size_t)i * 1024 * FI, wout_bf, 1024, FI, FI_PAD);

    rms_one<<<ROWS, 256, 0, stream>>>(x_res, naw + i * 1024, h);
    gemm_nt<0><<<dim3(32, 24), 256, 0, stream>>>(h, wqkv_bf, qkv_lin, nullptr, nullptr, 1024, 3072, 3072, 3072);
    gemm_nt<1><<<dim3(32, 1), 256, 0, stream>>>(h, wgm_bf, gm, nullptr, nullptr, 1024, 32, 32, 32);
    rope_qk<<<dim3(16, 64), 256, 0, stream>>>(qkv_lin, cost, sint, qb, kb);
    v_mix_pack<<<dim3(16, 64), 256, 0, stream>>>(qkv_lin, gm, vres, vtb, i);
    attn_fwd<<<1024, 256, 0, stream>>>(qb, kb, vtb, gm, attn);
    gemm_nt<2><<<dim3(32, 8), 256, 0, stream>>>(attn, wo_bf, x_res, nullptr, x_res, 1024, 1024, 1024, 1024);
    rms_ff<<<ROWS, 256, 0, stream>>>(x_res, nfw + i * 1024, ffw + i * 1024, h);
    gemm_nt<3><<<dim3(32, 22), 256, 0, stream>>>(h, wingt_bf, u, b_in + (size_t)i * 2 * FI + FI, nullptr, 1024, FI_PAD, FI, FI_PAD);
    gemm_nt<4><<<dim3(32, 22), 256, 0, stream>>>(h, wina_bf, u, b_in + (size_t)i * 2 * FI, nullptr, 1024, FI_PAD, FI, FI_PAD);
    gemm_nt<2><<<dim3(32, 8), 256, 0, stream>>>(u, wout_bf, x_res, b_out + i * 1024, x_res, FI_PAD, 1024, 1024, 1024);
  }
  rms_final<<<ROWS, 256, 0, stream>>>(x_res, fnw, (float*)d_out);
}